// Round 3
// baseline (147.229 us; speedup 1.0000x reference)
//
#include <hip/hip_runtime.h>
#include <hip/hip_bf16.h>
#include <math.h>

#define DMODEL 512
#define T_SEQ 2048
#define NH 8
#define DH 64
#define M_ROWS 4096
#define LDST 72   // padded LDS row stride (retention staging); 144 B = 16B-aligned
#define EPST 136  // epilogue repack stride (272 B = 16B-aligned, 2-way banks)
#define KV_BLOCKS 256  // proj blocks with bx in [4,12): producers of AT

typedef short s16x8 __attribute__((ext_vector_type(8)));
typedef short s16x4 __attribute__((ext_vector_type(4)));
typedef float f32x4 __attribute__((ext_vector_type(4)));

static __device__ __forceinline__ unsigned short f2bf(float f) {
  __hip_bfloat16 h = __float2bfloat16(f);
  return *(unsigned short*)&h;
}
static __device__ __forceinline__ float bf2f(unsigned short u) {
  union { unsigned int i; float f; } x; x.i = (unsigned int)u << 16; return x.f;
}
// async global->LDS 16B copy; LDS dest must be wave-uniform base + lane*16
static __device__ __forceinline__ void gld16(void* lds, const void* g) {
  __builtin_amdgcn_global_load_lds(
      (const __attribute__((address_space(1))) unsigned int*)g,
      (__attribute__((address_space(3))) unsigned int*)lds, 16, 0, 0);
}

// ---------------------------------------------------------------------------
// Fused prep: blocks 0..1023 cast x -> bf16; blocks 1024..1343 transpose+cast
// the 5 weight matrices into the stacked-row layout:
//   rows    0..511  : W_Q cols | rows 512..1535: [K_h|V_h] x 8 heads
//   rows 1536..2047 : W_G cols | rows 2048..2559: W_O cols
// Also zeroes the proj->scan ticket counter (workspace is poisoned between
// iterations, so it must be re-zeroed every replay; kernel boundary flushes).
// ---------------------------------------------------------------------------
__global__ __launch_bounds__(256) void prep_k(
    const float* __restrict__ x, unsigned short* __restrict__ Xb,
    const float* __restrict__ W0, const float* __restrict__ W1,
    const float* __restrict__ W2, const float* __restrict__ W3,
    const float* __restrict__ W4, unsigned short* __restrict__ WT,
    unsigned int* __restrict__ ctr)
{
  __shared__ __align__(16) unsigned short buf[64 * LDST];
  const int bid = blockIdx.x, tid = threadIdx.x;
  if (bid == 0 && tid == 0) *ctr = 0;
  if (bid < 1024) {
    const size_t i = ((size_t)bid * 256 + tid) * 8;
    float4 a = *(const float4*)&x[i];
    float4 b = *(const float4*)&x[i + 4];
    s16x8 o;
    o[0]=f2bf(a.x); o[1]=f2bf(a.y); o[2]=f2bf(a.z); o[3]=f2bf(a.w);
    o[4]=f2bf(b.x); o[5]=f2bf(b.y); o[6]=f2bf(b.z); o[7]=f2bf(b.w);
    *(s16x8*)&Xb[i] = o;
    return;
  }
  const int bid2 = bid - 1024;
  const int z = bid2 >> 6, rem = bid2 & 63;
  const int n0 = (rem & 7) * 64, k0 = (rem >> 3) * 64;
  const float* W = (z==0)?W0:(z==1)?W1:(z==2)?W2:(z==3)?W3:W4;
  int rowbase;
  if (z == 0)      rowbase = n0;
  else if (z == 1) rowbase = 512 + (n0 >> 6) * 128;        // K_h block
  else if (z == 2) rowbase = 512 + (n0 >> 6) * 128 + 64;   // V_h block
  else if (z == 3) rowbase = 1536 + n0;
  else             rowbase = 2048 + n0;
  #pragma unroll
  for (int r = 0; r < 4; ++r) {
    int idx = r * 256 + tid;
    int kr = idx >> 4, nc = idx & 15;
    float4 v = *(const float4*)&W[(size_t)(k0 + kr) * DMODEL + n0 + nc * 4];
    buf[(nc*4+0) * LDST + kr] = f2bf(v.x);
    buf[(nc*4+1) * LDST + kr] = f2bf(v.y);
    buf[(nc*4+2) * LDST + kr] = f2bf(v.z);
    buf[(nc*4+3) * LDST + kr] = f2bf(v.w);
  }
  __syncthreads();
  #pragma unroll
  for (int r = 0; r < 2; ++r) {
    int idx = r * 256 + tid;
    int nr = idx >> 3, c = idx & 7;
    *(s16x8*)&WT[((size_t)(rowbase + nr)) * DMODEL + k0 + c * 8] =
        *(const s16x8*)&buf[nr * LDST + c * 8];
  }
}

// ---------------------------------------------------------------------------
// Projection GEMM + fused KV outer product; b128 epilogue via LDS repack.
// FUSED SCAN: KV blocks (bx in [4,12)) ticket a device counter after their
// AT stores; 64 scanner blocks (bx in [4,12), by%4==0) spin until all 256
// KV blocks are done, then run the wide prefix scan in-place. Deadlock-safe:
// LDS 34 KB -> 4 blocks/CU capacity (1024) >= grid (512), so all blocks are
// co-resident and producers are never queued behind a spinner.
// ---------------------------------------------------------------------------
__global__ __launch_bounds__(256) void proj_kv_k(
    const unsigned short* __restrict__ A, const unsigned short* __restrict__ BT,
    unsigned short* __restrict__ Qb, unsigned short* __restrict__ Kb,
    unsigned short* __restrict__ Vb, unsigned short* __restrict__ Gb,
    float* __restrict__ AT, unsigned short* __restrict__ Sg,
    unsigned int* __restrict__ ctr)
{
  __shared__ __align__(16) unsigned short smem[128 * EPST]; // >= 2*128*64
  unsigned short* As = smem;
  unsigned short* Bs = smem + 128 * 64;
  const int ng0 = blockIdx.x * 128;
  const int m0 = blockIdx.y * 128;
  const int tid = threadIdx.x;
  const int wave = tid >> 6, lane = tid & 63;
  const int wm = wave >> 1, wn = wave & 1;
  const int n = lane & 15, quad = lane >> 4;

  int srow[4], scol[4];
  #pragma unroll
  for (int r = 0; r < 4; ++r) {
    int idx = r * 256 + tid;
    srow[r] = idx >> 3;
    scol[r] = ((idx & 7) ^ (srow[r] & 7)) * 8;
  }

  f32x4 acc[4][4];
  #pragma unroll
  for (int mi = 0; mi < 4; ++mi)
    #pragma unroll
    for (int ni = 0; ni < 4; ++ni) acc[mi][ni] = (f32x4){0.f,0.f,0.f,0.f};

  for (int k0 = 0; k0 < 512; k0 += 64) {
    #pragma unroll
    for (int r = 0; r < 4; ++r) {
      int idx = r * 256 + tid;
      gld16(&As[idx * 8], &A[(size_t)(m0 + srow[r]) * DMODEL + k0 + scol[r]]);
      gld16(&Bs[idx * 8], &BT[(size_t)(ng0 + srow[r]) * DMODEL + k0 + scol[r]]);
    }
    __syncthreads();
    #pragma unroll
    for (int kk = 0; kk < 2; ++kk) {
      s16x8 af[4], bf[4];
      #pragma unroll
      for (int mi = 0; mi < 4; ++mi) {
        int R = wm*64 + mi*16 + n, cc = (kk*4 + quad) ^ (n & 7);
        af[mi] = *(const s16x8*)&As[R * 64 + cc * 8];
      }
      #pragma unroll
      for (int ni = 0; ni < 4; ++ni) {
        int R = wn*64 + ni*16 + n, cc = (kk*4 + quad) ^ (n & 7);
        bf[ni] = *(const s16x8*)&Bs[R * 64 + cc * 8];
      }
      #pragma unroll
      for (int mi = 0; mi < 4; ++mi)
        #pragma unroll
        for (int ni = 0; ni < 4; ++ni)
          acc[mi][ni] = __builtin_amdgcn_mfma_f32_16x16x32_bf16(
              af[mi], bf[ni], acc[mi][ni], 0, 0, 0);
    }
    __syncthreads();
  }

  // ---- epilogue: repack acc via LDS (128 x EPST) -> b128 global stores ----
  unsigned short* Ep = smem;
  #pragma unroll
  for (int mi = 0; mi < 4; ++mi)
    #pragma unroll
    for (int ni = 0; ni < 4; ++ni)
      #pragma unroll
      for (int r = 0; r < 4; ++r)
        Ep[(wm*64 + mi*16 + quad*4 + r) * EPST + wn*64 + ni*16 + n] =
            f2bf(acc[mi][ni][r]);
  __syncthreads();

  const int bx = blockIdx.x;
  if (bx < 4 || bx >= 12) {
    unsigned short* Cz = (bx < 4) ? Qb : Gb;
    const int n0 = (bx < 4) ? ng0 : (ng0 - 1536);
    #pragma unroll
    for (int t = 0; t < 8; ++t) {
      int idx = t * 256 + tid;
      int row = idx >> 4, u = idx & 15;
      *(s16x8*)&Cz[(size_t)(m0 + row) * DMODEL + n0 + u * 8] =
          *(const s16x8*)&Ep[row * EPST + u * 8];
    }
    return;
  }

  // KV tile: cols 0..63 = K_h, 64..127 = V_h
  const int h = (ng0 - 512) >> 7;
  const float lg = log2f(1.0f - exp2f(-5.0f - (float)h));
  #pragma unroll
  for (int t = 0; t < 4; ++t) {
    int idx = t * 256 + tid;
    int row = idx >> 3, u = idx & 7;
    *(s16x8*)&Kb[(size_t)(m0 + row) * DMODEL + h*DH + u * 8] =
        *(const s16x8*)&Ep[row * EPST + u * 8];
    *(s16x8*)&Vb[(size_t)(m0 + row) * DMODEL + h*DH + u * 8] =
        *(const s16x8*)&Ep[row * EPST + 64 + u * 8];
  }

  // fused AT: per 64-row chunk, stage scaled K^T and V^T, 8 MFMAs, store
  unsigned short* Kt = smem;                 // [d1][m], LDST stride
  unsigned short* Vt = smem + 64 * LDST;
  #pragma unroll
  for (int cc2 = 0; cc2 < 2; ++cc2) {
    __syncthreads();   // orders Ep reads / prev chunk's MFMA before restage
    if (wm == cc2) {
      unsigned short* Tt = (wn == 0) ? Kt : Vt;
      #pragma unroll
      for (int mi = 0; mi < 4; ++mi)
        #pragma unroll
        for (int r = 0; r < 4; ++r) {
          int m = mi*16 + quad*4 + r;
          float sc = (wn == 0) ? exp2f((float)(64 - m) * lg) : 1.0f;
          #pragma unroll
          for (int ni = 0; ni < 4; ++ni)
            Tt[(ni*16 + n) * LDST + m] = f2bf(acc[mi][ni][r] * sc);
        }
    }
    __syncthreads();
    f32x4 at[4];
    #pragma unroll
    for (int j = 0; j < 4; ++j) at[j] = (f32x4){0.f,0.f,0.f,0.f};
    #pragma unroll
    for (int kk = 0; kk < 2; ++kk) {
      s16x8 a = *(const s16x8*)&Vt[(wave*16 + n) * LDST + kk*32 + quad*8];
      #pragma unroll
      for (int j = 0; j < 4; ++j) {
        s16x8 bf = *(const s16x8*)&Kt[(j*16 + n) * LDST + kk*32 + quad*8];
        at[j] = __builtin_amdgcn_mfma_f32_16x16x32_bf16(a, bf, at[j], 0, 0, 0);
      }
    }
    const int gr = m0 + cc2 * 64;
    const int bb = gr >> 11, cchunk = (gr & 2047) >> 6;
    float* Ab = AT + (((size_t)(bb * NH + h) * 32 + cchunk) << 12);
    #pragma unroll
    for (int j = 0; j < 4; ++j)
      #pragma unroll
      for (int r = 0; r < 4; ++r)
        Ab[(wave*16 + quad*4 + r) * 64 + j*16 + n] = at[j][r];
  }

  // ---- ticket: AT stores done, make them device-visible, count this block
  __threadfence();          // release: flush this thread's AT stores (agent)
  __syncthreads();          // all threads fenced before thread 0 tickets
  if (tid == 0) atomicAdd(ctr, 1u);

  // ---- scanner blocks: wait for all 256 KV blocks, then prefix scan ------
  const int by = blockIdx.y;
  if ((by & 3) != 0) return;
  // sid in [0,64): 8 bx values x 8 by values
  const int sid = (bx - 4) * 8 + (by >> 2);
  if (tid == 0) {
    while (__hip_atomic_load(ctr, __ATOMIC_ACQUIRE,
                             __HIP_MEMORY_SCOPE_AGENT) < KV_BLOCKS) {
      __builtin_amdgcn_s_sleep(8);
    }
  }
  __syncthreads();
  __threadfence();          // acquire side: invalidate stale cached AT lines

  // wide scan slice (identical math to the former scan_k)
  const int bh2 = sid >> 2;           // b*NH + h, 0..15
  const int rg = sid & 3;             // row group (16 rows each)
  const int h2 = bh2 & 7;
  const float lg2 = log2f(1.0f - exp2f(-5.0f - (float)h2));
  const float w = exp2f(64.0f * lg2); // gamma^64
  const int d2 = rg * 16 + (tid >> 4);     // state row 0..63
  const int col4 = (tid & 15) * 4;         // first owned column
  const int gcol = (((col4 >> 3) ^ (d2 & 7)) * 8) + (col4 & 7); // swizzled
  const float* Ab2 = AT + (((size_t)bh2 * 32) << 12) + (size_t)d2 * 64 + col4;
  unsigned short* Sr = Sg + (((size_t)bh2 * 32) << 12) + (size_t)d2 * 64 + gcol;
  float4 S = {0.f, 0.f, 0.f, 0.f};
  #pragma unroll 8
  for (int c = 0; c < 32; ++c) {
    float4 a = *(const float4*)(Ab2 + ((size_t)c << 12));
    s16x4 st;
    st[0] = (short)f2bf(S.x); st[1] = (short)f2bf(S.y);
    st[2] = (short)f2bf(S.z); st[3] = (short)f2bf(S.w);
    *(s16x4*)(Sr + ((size_t)c << 12)) = st;   // 8B store, 8B-aligned
    S.x = fmaf(w, S.x, a.x); S.y = fmaf(w, S.y, a.y);
    S.z = fmaf(w, S.z, a.z); S.w = fmaf(w, S.w, a.w);
  }
}

// ---------------------------------------------------------------------------
// Fused retention output + GroupNorm + gate + SiLU. S_c staged via gld16.
// ---------------------------------------------------------------------------
__global__ __launch_bounds__(256) void ret_o2_k(
    const unsigned short* __restrict__ Qb, const unsigned short* __restrict__ Kb,
    const unsigned short* __restrict__ Vb, const unsigned short* __restrict__ Sg,
    const unsigned short* __restrict__ Gg, const float* __restrict__ gnw,
    const float* __restrict__ gnb, unsigned short* __restrict__ Sb)
{
  __shared__ __align__(16) unsigned short Qs[64 * 64];    // swizzled
  __shared__ __align__(16) unsigned short Ks[64 * 64];    // swizzled
  __shared__ __align__(16) unsigned short Ss[64 * 64];    // swizzled (pre-swz global)
  __shared__ __align__(16) unsigned short Vst[64 * LDST]; // [d2][m]
  __shared__ __align__(16) unsigned short Ps[64 * LDST];
  const int c = (int)blockIdx.x;
  const int h = blockIdx.y, b = blockIdx.z;
  const int bh = b * NH + h;
  const int tid = threadIdx.x;
  const int wave = tid >> 6, lane = tid & 63;
  const int n = lane & 15, quad = lane >> 4;
  const size_t base = ((size_t)b * T_SEQ + (size_t)c * 64) * DMODEL + h * DH;
  const float lg = log2f(1.0f - exp2f(-5.0f - (float)h));

  // stage Q, K, S (async; Q/K swizzled at source index, S pre-swizzled content)
  const unsigned short* Sgt = Sg + (((size_t)bh * 32 + (size_t)c) << 12);
  #pragma unroll
  for (int r = 0; r < 2; ++r) {
    int idx = r * 256 + tid;
    int row = idx >> 3, sc = ((idx & 7) ^ (row & 7)) * 8;
    gld16(&Qs[idx * 8], &Qb[base + (size_t)row * DMODEL + sc]);
    gld16(&Ks[idx * 8], &Kb[base + (size_t)row * DMODEL + sc]);
    gld16(&Ss[idx * 8], &Sgt[(size_t)idx * 8]);
  }
  // V^T staging (VGPR transpose path)
  #pragma unroll
  for (int r = 0; r < 2; ++r) {
    int idx = r * 256 + tid;
    int m = idx & 63, ch = idx >> 6;
    s16x8 vv = *(const s16x8*)&Vb[base + (size_t)m * DMODEL + ch * 8];
    #pragma unroll
    for (int e = 0; e < 8; ++e)
      Vst[(ch * 8 + e) * LDST + m] = ((unsigned short*)&vv)[e];
  }
  __syncthreads();  // drains Q/K/S gld16 + Vst writes

  f32x4 s[4], u[4];
  #pragma unroll
  for (int j = 0; j < 4; ++j) {
    s[j] = (f32x4){0.f,0.f,0.f,0.f};
    u[j] = (f32x4){0.f,0.f,0.f,0.f};
  }
  const int RA = wave*16 + n;
  #pragma unroll
  for (int kk = 0; kk < 2; ++kk) {
    s16x8 a = *(const s16x8*)&Qs[RA * 64 + (((kk*4 + quad) ^ (RA & 7)) * 8)];
    #pragma unroll
    for (int j = 0; j < 4; ++j) {
      int RB = j*16 + n;
      int cc = ((kk*4 + quad) ^ (RB & 7)) * 8;
      s16x8 bk = *(const s16x8*)&Ks[RB * 64 + cc];
      s[j] = __builtin_amdgcn_mfma_f32_16x16x32_bf16(a, bk, s[j], 0, 0, 0);
      s16x8 bs = *(const s16x8*)&Ss[RB * 64 + cc];
      u[j] = __builtin_amdgcn_mfma_f32_16x16x32_bf16(a, bs, u[j], 0, 0, 0);
    }
  }

  float rowf[4], colf[4];
  #pragma unroll
  for (int r = 0; r < 4; ++r) rowf[r] = exp2f((float)(wave*16 + quad*4 + r) * lg);
  #pragma unroll
  for (int j = 0; j < 4; ++j) colf[j] = exp2f(-(float)(j*16 + n) * lg);

  #pragma unroll
  for (int j = 0; j < 4; ++j)
    #pragma unroll
    for (int r = 0; r < 4; ++r) {
      int i = wave*16 + quad*4 + r, mcol = j*16 + n;
      float v = (mcol <= i) ? s[j][r] * 0.125f * rowf[r] * colf[j] : 0.0f;
      Ps[i * LDST + mcol] = f2bf(v);
    }
  __syncthreads();  // all QK reads of Qs done; Ps ready

  // prefetch G tile into Qs (now dead) for the epilogue
  #pragma unroll
  for (int r = 0; r < 2; ++r) {
    int idx = r * 256 + tid;
    int row = idx >> 3, sc = ((idx & 7) ^ (row & 7)) * 8;
    gld16(&Qs[idx * 8], &Gg[base + (size_t)row * DMODEL + sc]);
  }

  f32x4 acc[4];
  #pragma unroll
  for (int j = 0; j < 4; ++j) acc[j] = (f32x4){0.f,0.f,0.f,0.f};
  #pragma unroll
  for (int kk = 0; kk < 2; ++kk) {
    s16x8 a = *(const s16x8*)&Ps[RA * LDST + kk*32 + quad*8];
    #pragma unroll
    for (int j = 0; j < 4; ++j) {
      s16x8 bf = *(const s16x8*)&Vst[(j*16 + n) * LDST + kk*32 + quad*8];
      acc[j] = __builtin_amdgcn_mfma_f32_16x16x32_bf16(a, bf, acc[j], 0, 0, 0);
    }
  }

  float ov[4][4];
  #pragma unroll
  for (int j = 0; j < 4; ++j)
    #pragma unroll
    for (int r = 0; r < 4; ++r)
      ov[j][r] = acc[j][r] + 0.125f * rowf[r] * u[j][r];

  float gw[4], gb[4];
  #pragma unroll
  for (int j = 0; j < 4; ++j) {
    gw[j] = gnw[h*DH + j*16 + n];
    gb[j] = gnb[h*DH + j*16 + n];
  }

  float normed[4][4];
  #pragma unroll
  for (int r = 0; r < 4; ++r) {
    float sum = ov[0][r] + ov[1][r] + ov[2][r] + ov[3][r];
    float sq  = ov[0][r]*ov[0][r] + ov[1][r]*ov[1][r]
              + ov[2][r]*ov[2][r] + ov[3][r]*ov[3][r];
    #pragma unroll
    for (int off = 8; off > 0; off >>= 1) {
      sum += __shfl_xor(sum, off, 64);
      sq  += __shfl_xor(sq,  off, 64);
    }
    const float mean = sum * (1.0f / 64.0f);
    float var = sq * (1.0f / 64.0f) - mean * mean;
    var = fmaxf(var, 0.0f);
    const float rstd = rsqrtf(var + 1e-5f);
    #pragma unroll
    for (int j = 0; j < 4; ++j)
      normed[j][r] = (ov[j][r] - mean) * rstd * gw[j] + gb[j];
  }

  __syncthreads();  // all PV reads of Ps done; G gld16 drained

  #pragma unroll
  for (int r = 0; r < 4; ++r) {
    const int i = wave*16 + quad*4 + r;
    #pragma unroll
    for (int j = 0; j < 4; ++j) {
      const int col = j*16 + n;
      const int gidx = i * 64 + (((col >> 3) ^ (i & 7)) * 8) + (col & 7);
      float uu = bf2f(Qs[gidx]) + normed[j][r];
      Ps[i * LDST + col] = f2bf(uu / (1.0f + expf(-uu)));
    }
  }
  __syncthreads();
  #pragma unroll
  for (int t = 0; t < 2; ++t) {
    int idx = t * 256 + tid;
    int row = idx >> 3, u8 = idx & 7;
    *(s16x8*)&Sb[base + (size_t)row * DMODEL + u8 * 8] =
        *(const s16x8*)&Ps[row * LDST + u8 * 8];
  }
}

// ---------------------------------------------------------------------------
// Output GEMM: out = Sb(4096x512 bf16) @ WO^T, fp32.
// ---------------------------------------------------------------------------
__global__ __launch_bounds__(256) void out_gemm_k(
    const unsigned short* __restrict__ A, const unsigned short* __restrict__ BT,
    float* __restrict__ out)
{
  __shared__ __align__(16) unsigned short As[64 * 64];
  __shared__ __align__(16) unsigned short Bs[64 * 64];
  const int n0 = blockIdx.x * 64;
  const int m0 = blockIdx.y * 64;
  const int tid = threadIdx.x;
  const int wave = tid >> 6, lane = tid & 63;
  const int wm = wave >> 1, wn = wave & 1;
  const int n = lane & 15, quad = lane >> 4;

  int srow[2], scol[2];
  #pragma unroll
  for (int r = 0; r < 2; ++r) {
    int idx = r * 256 + tid;
    srow[r] = idx >> 3;
    scol[r] = ((idx & 7) ^ (srow[r] & 7)) * 8;
  }

  f32x4 acc[2][2];
  #pragma unroll
  for (int mi = 0; mi < 2; ++mi)
    #pragma unroll
    for (int ni = 0; ni < 2; ++ni) acc[mi][ni] = (f32x4){0.f,0.f,0.f,0.f};

  for (int k0 = 0; k0 < 512; k0 += 64) {
    #pragma unroll
    for (int r = 0; r < 2; ++r) {
      int idx = r * 256 + tid;
      gld16(&As[idx * 8], &A[(size_t)(m0 + srow[r]) * DMODEL + k0 + scol[r]]);
      gld16(&Bs[idx * 8], &BT[(size_t)(n0 + srow[r]) * DMODEL + k0 + scol[r]]);
    }
    __syncthreads();
    #pragma unroll
    for (int kk = 0; kk < 2; ++kk) {
      s16x8 af[2], bf[2];
      #pragma unroll
      for (int mi = 0; mi < 2; ++mi) {
        int R = wm*32 + mi*16 + n, cc = (kk*4 + quad) ^ (n & 7);
        af[mi] = *(const s16x8*)&As[R * 64 + cc * 8];
      }
      #pragma unroll
      for (int ni = 0; ni < 2; ++ni) {
        int R = wn*32 + ni*16 + n, cc = (kk*4 + quad) ^ (n & 7);
        bf[ni] = *(const s16x8*)&Bs[R * 64 + cc * 8];
      }
      #pragma unroll
      for (int mi = 0; mi < 2; ++mi)
        #pragma unroll
        for (int ni = 0; ni < 2; ++ni)
          acc[mi][ni] = __builtin_amdgcn_mfma_f32_16x16x32_bf16(
              af[mi], bf[ni], acc[mi][ni], 0, 0, 0);
    }
    __syncthreads();
  }

  #pragma unroll
  for (int mi = 0; mi < 2; ++mi)
    #pragma unroll
    for (int ni = 0; ni < 2; ++ni)
      #pragma unroll
      for (int r = 0; r < 4; ++r)
        out[(size_t)(m0 + wm*32 + mi*16 + quad*4 + r) * DMODEL +
            n0 + wn*32 + ni*16 + n] = acc[mi][ni][r];
}

// ---------------------------------------------------------------------------
extern "C" void kernel_launch(void* const* d_in, const int* in_sizes, int n_in,
                              void* d_out, int out_size, void* d_ws, size_t ws_size,
                              hipStream_t stream) {
  const float* x   = (const float*)d_in[0];
  const float* WQ  = (const float*)d_in[1];
  const float* WK  = (const float*)d_in[2];
  const float* WV  = (const float*)d_in[3];
  const float* WG  = (const float*)d_in[4];
  const float* WO  = (const float*)d_in[5];
  const float* gnw = (const float*)d_in[6];
  const float* gnb = (const float*)d_in[7];
  float* out = (float*)d_out;

  char* ws = (char*)d_ws;
  unsigned short* Xb = (unsigned short*)(ws);                 // 4 MB
  unsigned short* Qb = (unsigned short*)(ws + 4  * (1<<20));  // 4 MB
  unsigned short* Kb = (unsigned short*)(ws + 8  * (1<<20));  // 4 MB
  unsigned short* Vb = (unsigned short*)(ws + 12 * (1<<20));  // 4 MB
  unsigned short* G  = (unsigned short*)(ws + 16 * (1<<20));  // 4 MB (bf16)
  float* AT  = (float*)(ws + 24 * (1<<20));                   // 8 MB
  unsigned short* Sb = (unsigned short*)(ws + 32 * (1<<20));  // 4 MB
  unsigned short* Sg = (unsigned short*)(ws + 36 * (1<<20));  // 4 MB (bf16 states)
  unsigned short* WT = (unsigned short*)(ws + 40 * (1<<20));  // 2.5 MB
  unsigned int*  ctr = (unsigned int*)(ws + 44 * (1<<20));    // 4 B ticket
  (void)ws_size;

  // 1) fused cast-x + weight transpose/stacking (+ counter zeroing)
  prep_k<<<dim3(1024 + 320), 256, 0, stream>>>(x, Xb, WQ, WK, WV, WG, WO, WT, ctr);
  // 2) projections + fused KV outer products + fused ticket-gated prefix scan
  proj_kv_k<<<dim3(16, M_ROWS / 128), 256, 0, stream>>>(
      Xb, WT, Qb, Kb, Vb, G, AT, Sg, ctr);
  // 3) fused retention output + GroupNorm + gate + SiLU
  ret_o2_k<<<dim3(T_SEQ / 64, NH, 2), 256, 0, stream>>>(
      Qb, Kb, Vb, Sg, G, gnw, gnb, Sb);
  // 4) output projection (fp32 out), 64x64 tiles, 512 blocks = 2/CU
  out_gemm_k<<<dim3(8, M_ROWS / 64), 256, 0, stream>>>(
      Sb, WT + 2048 * DMODEL, out);
}

// Round 4
// 113.341 us; speedup vs baseline: 1.2990x; 1.2990x over previous
//
#include <hip/hip_runtime.h>
#include <hip/hip_bf16.h>
#include <math.h>

#define DMODEL 512
#define T_SEQ 2048
#define NH 8
#define DH 64
#define M_ROWS 4096
#define LDST 72   // padded LDS row stride (retention staging); 144 B = 16B-aligned
#define EPST 136  // epilogue repack stride (272 B = 16B-aligned, 2-way banks)

typedef short s16x8 __attribute__((ext_vector_type(8)));
typedef short s16x4 __attribute__((ext_vector_type(4)));
typedef float f32x4 __attribute__((ext_vector_type(4)));

static __device__ __forceinline__ unsigned short f2bf(float f) {
  __hip_bfloat16 h = __float2bfloat16(f);
  return *(unsigned short*)&h;
}
static __device__ __forceinline__ float bf2f(unsigned short u) {
  union { unsigned int i; float f; } x; x.i = (unsigned int)u << 16; return x.f;
}
// async global->LDS 16B copy; LDS dest must be wave-uniform base + lane*16
static __device__ __forceinline__ void gld16(void* lds, const void* g) {
  __builtin_amdgcn_global_load_lds(
      (const __attribute__((address_space(1))) unsigned int*)g,
      (__attribute__((address_space(3))) unsigned int*)lds, 16, 0, 0);
}

// ---------------------------------------------------------------------------
// Fused prep: blocks 0..1023 cast x -> bf16; blocks 1024..1343 transpose+cast
// the 5 weight matrices into the stacked-row layout:
//   rows    0..511  : W_Q cols | rows 512..1535: [K_h|V_h] x 8 heads
//   rows 1536..2047 : W_G cols | rows 2048..2559: W_O cols
// ---------------------------------------------------------------------------
__global__ __launch_bounds__(256) void prep_k(
    const float* __restrict__ x, unsigned short* __restrict__ Xb,
    const float* __restrict__ W0, const float* __restrict__ W1,
    const float* __restrict__ W2, const float* __restrict__ W3,
    const float* __restrict__ W4, unsigned short* __restrict__ WT)
{
  __shared__ __align__(16) unsigned short buf[64 * LDST];
  const int bid = blockIdx.x, tid = threadIdx.x;
  if (bid < 1024) {
    const size_t i = ((size_t)bid * 256 + tid) * 8;
    float4 a = *(const float4*)&x[i];
    float4 b = *(const float4*)&x[i + 4];
    s16x8 o;
    o[0]=f2bf(a.x); o[1]=f2bf(a.y); o[2]=f2bf(a.z); o[3]=f2bf(a.w);
    o[4]=f2bf(b.x); o[5]=f2bf(b.y); o[6]=f2bf(b.z); o[7]=f2bf(b.w);
    *(s16x8*)&Xb[i] = o;
    return;
  }
  const int bid2 = bid - 1024;
  const int z = bid2 >> 6, rem = bid2 & 63;
  const int n0 = (rem & 7) * 64, k0 = (rem >> 3) * 64;
  const float* W = (z==0)?W0:(z==1)?W1:(z==2)?W2:(z==3)?W3:W4;
  int rowbase;
  if (z == 0)      rowbase = n0;
  else if (z == 1) rowbase = 512 + (n0 >> 6) * 128;        // K_h block
  else if (z == 2) rowbase = 512 + (n0 >> 6) * 128 + 64;   // V_h block
  else if (z == 3) rowbase = 1536 + n0;
  else             rowbase = 2048 + n0;
  #pragma unroll
  for (int r = 0; r < 4; ++r) {
    int idx = r * 256 + tid;
    int kr = idx >> 4, nc = idx & 15;
    float4 v = *(const float4*)&W[(size_t)(k0 + kr) * DMODEL + n0 + nc * 4];
    buf[(nc*4+0) * LDST + kr] = f2bf(v.x);
    buf[(nc*4+1) * LDST + kr] = f2bf(v.y);
    buf[(nc*4+2) * LDST + kr] = f2bf(v.z);
    buf[(nc*4+3) * LDST + kr] = f2bf(v.w);
  }
  __syncthreads();
  #pragma unroll
  for (int r = 0; r < 2; ++r) {
    int idx = r * 256 + tid;
    int nr = idx >> 3, c = idx & 7;
    *(s16x8*)&WT[((size_t)(rowbase + nr)) * DMODEL + k0 + c * 8] =
        *(const s16x8*)&buf[nr * LDST + c * 8];
  }
}

// ---------------------------------------------------------------------------
// Projection GEMM + fused KV outer product; b128 epilogue via LDS repack.
// 1-D grid 512 with XCD-chunked swizzle: hw%8 = XCD (dispatch round-robin),
// each XCD gets 64 consecutive logical ids = 4 full A row-panels -> A panels
// (4x128KB) + WT (2.5MB) resident in that XCD's 4MB L2.
// ---------------------------------------------------------------------------
__global__ __launch_bounds__(256) void proj_kv_k(
    const unsigned short* __restrict__ A, const unsigned short* __restrict__ BT,
    unsigned short* __restrict__ Qb, unsigned short* __restrict__ Kb,
    unsigned short* __restrict__ Vb, unsigned short* __restrict__ Gb,
    float* __restrict__ AT)
{
  __shared__ __align__(16) unsigned short smem[128 * EPST]; // >= 2*128*64
  unsigned short* As = smem;
  unsigned short* Bs = smem + 128 * 64;
  const int hw = (int)blockIdx.x;
  const int lg = (hw & 7) * 64 + (hw >> 3);   // bijective: 512 = 8 * 64
  const int bx = lg & 15, by = lg >> 4;
  const int ng0 = bx * 128;
  const int m0 = by * 128;
  const int tid = threadIdx.x;
  const int wave = tid >> 6, lane = tid & 63;
  const int wm = wave >> 1, wn = wave & 1;
  const int n = lane & 15, quad = lane >> 4;

  int srow[4], scol[4];
  #pragma unroll
  for (int r = 0; r < 4; ++r) {
    int idx = r * 256 + tid;
    srow[r] = idx >> 3;
    scol[r] = ((idx & 7) ^ (srow[r] & 7)) * 8;
  }

  f32x4 acc[4][4];
  #pragma unroll
  for (int mi = 0; mi < 4; ++mi)
    #pragma unroll
    for (int ni = 0; ni < 4; ++ni) acc[mi][ni] = (f32x4){0.f,0.f,0.f,0.f};

  for (int k0 = 0; k0 < 512; k0 += 64) {
    #pragma unroll
    for (int r = 0; r < 4; ++r) {
      int idx = r * 256 + tid;
      gld16(&As[idx * 8], &A[(size_t)(m0 + srow[r]) * DMODEL + k0 + scol[r]]);
      gld16(&Bs[idx * 8], &BT[(size_t)(ng0 + srow[r]) * DMODEL + k0 + scol[r]]);
    }
    __syncthreads();
    #pragma unroll
    for (int kk = 0; kk < 2; ++kk) {
      s16x8 af[4], bf[4];
      #pragma unroll
      for (int mi = 0; mi < 4; ++mi) {
        int R = wm*64 + mi*16 + n, cc = (kk*4 + quad) ^ (n & 7);
        af[mi] = *(const s16x8*)&As[R * 64 + cc * 8];
      }
      #pragma unroll
      for (int ni = 0; ni < 4; ++ni) {
        int R = wn*64 + ni*16 + n, cc = (kk*4 + quad) ^ (n & 7);
        bf[ni] = *(const s16x8*)&Bs[R * 64 + cc * 8];
      }
      #pragma unroll
      for (int mi = 0; mi < 4; ++mi)
        #pragma unroll
        for (int ni = 0; ni < 4; ++ni)
          acc[mi][ni] = __builtin_amdgcn_mfma_f32_16x16x32_bf16(
              af[mi], bf[ni], acc[mi][ni], 0, 0, 0);
    }
    __syncthreads();
  }

  // ---- epilogue: repack acc via LDS (128 x EPST) -> b128 global stores ----
  unsigned short* Ep = smem;
  #pragma unroll
  for (int mi = 0; mi < 4; ++mi)
    #pragma unroll
    for (int ni = 0; ni < 4; ++ni)
      #pragma unroll
      for (int r = 0; r < 4; ++r)
        Ep[(wm*64 + mi*16 + quad*4 + r) * EPST + wn*64 + ni*16 + n] =
            f2bf(acc[mi][ni][r]);
  __syncthreads();

  if (bx < 4 || bx >= 12) {
    unsigned short* Cz = (bx < 4) ? Qb : Gb;
    const int n0 = (bx < 4) ? ng0 : (ng0 - 1536);
    #pragma unroll
    for (int t = 0; t < 8; ++t) {
      int idx = t * 256 + tid;
      int row = idx >> 4, u = idx & 15;
      *(s16x8*)&Cz[(size_t)(m0 + row) * DMODEL + n0 + u * 8] =
          *(const s16x8*)&Ep[row * EPST + u * 8];
    }
    return;
  }

  // KV tile: cols 0..63 = K_h, 64..127 = V_h
  const int h = (ng0 - 512) >> 7;
  const float lg2 = log2f(1.0f - exp2f(-5.0f - (float)h));
  #pragma unroll
  for (int t = 0; t < 4; ++t) {
    int idx = t * 256 + tid;
    int row = idx >> 3, u = idx & 7;
    *(s16x8*)&Kb[(size_t)(m0 + row) * DMODEL + h*DH + u * 8] =
        *(const s16x8*)&Ep[row * EPST + u * 8];
    *(s16x8*)&Vb[(size_t)(m0 + row) * DMODEL + h*DH + u * 8] =
        *(const s16x8*)&Ep[row * EPST + 64 + u * 8];
  }

  // fused AT: per 64-row chunk, stage scaled K^T and V^T, 8 MFMAs, store
  unsigned short* Kt = smem;                 // [d1][m], LDST stride
  unsigned short* Vt = smem + 64 * LDST;
  #pragma unroll
  for (int cc2 = 0; cc2 < 2; ++cc2) {
    __syncthreads();   // orders Ep reads / prev chunk's MFMA before restage
    if (wm == cc2) {
      unsigned short* Tt = (wn == 0) ? Kt : Vt;
      #pragma unroll
      for (int mi = 0; mi < 4; ++mi)
        #pragma unroll
        for (int r = 0; r < 4; ++r) {
          int m = mi*16 + quad*4 + r;
          float sc = (wn == 0) ? exp2f((float)(64 - m) * lg2) : 1.0f;
          #pragma unroll
          for (int ni = 0; ni < 4; ++ni)
            Tt[(ni*16 + n) * LDST + m] = f2bf(acc[mi][ni][r] * sc);
        }
    }
    __syncthreads();
    f32x4 at[4];
    #pragma unroll
    for (int j = 0; j < 4; ++j) at[j] = (f32x4){0.f,0.f,0.f,0.f};
    #pragma unroll
    for (int kk = 0; kk < 2; ++kk) {
      s16x8 a = *(const s16x8*)&Vt[(wave*16 + n) * LDST + kk*32 + quad*8];
      #pragma unroll
      for (int j = 0; j < 4; ++j) {
        s16x8 bf = *(const s16x8*)&Kt[(j*16 + n) * LDST + kk*32 + quad*8];
        at[j] = __builtin_amdgcn_mfma_f32_16x16x32_bf16(a, bf, at[j], 0, 0, 0);
      }
    }
    const int gr = m0 + cc2 * 64;
    const int bb = gr >> 11, cchunk = (gr & 2047) >> 6;
    float* Ab = AT + (((size_t)(bb * NH + h) * 32 + cchunk) << 12);
    #pragma unroll
    for (int j = 0; j < 4; ++j)
      #pragma unroll
      for (int r = 0; r < 4; ++r)
        Ab[(wave*16 + quad*4 + r) * 64 + j*16 + n] = at[j][r];
  }
}

// ---------------------------------------------------------------------------
// Sequential prefix scan over chunk states, WIDE version.
//   S_{c+1} = gamma_h^64 * S_c + A_c,  S_0 = 0
// 64 blocks (4 per (b,h), 16 state-rows each); each thread owns ONE float4
// column slice of one row. #pragma unroll 8 lets 8 iterations' independent
// loads fly while the dependent FMA chain trails (~2 MB in flight chip-wide).
// Emits bf16, pre-XOR-swizzled in the column-block index so ret_o2_k stages
// with linear gld16 and reads with the same XOR pattern as Ks.
// ---------------------------------------------------------------------------
__global__ __launch_bounds__(256) void scan_k(
    const float* __restrict__ AT, unsigned short* __restrict__ Sg)
{
  const int bh = blockIdx.x >> 2;     // b*NH + h, 0..15
  const int rg = blockIdx.x & 3;      // row group (16 rows each)
  const int h = bh & 7;
  const int tid = threadIdx.x;
  const float lg = log2f(1.0f - exp2f(-5.0f - (float)h));
  const float w = exp2f(64.0f * lg);  // gamma^64
  const int d2 = rg * 16 + (tid >> 4);     // state row 0..63
  const int col4 = (tid & 15) * 4;         // first owned column
  const int gcol = (((col4 >> 3) ^ (d2 & 7)) * 8) + (col4 & 7); // swizzled
  const float* Ab = AT + (((size_t)bh * 32) << 12) + (size_t)d2 * 64 + col4;
  unsigned short* Sr = Sg + (((size_t)bh * 32) << 12) + (size_t)d2 * 64 + gcol;
  float4 S = {0.f, 0.f, 0.f, 0.f};
  #pragma unroll 8
  for (int c = 0; c < 32; ++c) {
    float4 a = *(const float4*)(Ab + ((size_t)c << 12));
    s16x4 st;
    st[0] = (short)f2bf(S.x); st[1] = (short)f2bf(S.y);
    st[2] = (short)f2bf(S.z); st[3] = (short)f2bf(S.w);
    *(s16x4*)(Sr + ((size_t)c << 12)) = st;   // 8B store, 8B-aligned
    S.x = fmaf(w, S.x, a.x); S.y = fmaf(w, S.y, a.y);
    S.z = fmaf(w, S.z, a.z); S.w = fmaf(w, S.w, a.w);
  }
}

// ---------------------------------------------------------------------------
// Fused retention output + GroupNorm + gate + SiLU. S_c staged via gld16.
// No XCD swizzle: blocks sharing a row-panel (same c) are stride-32 apart in
// dispatch order and 32%8==0, so they already co-locate per XCD.
// ---------------------------------------------------------------------------
__global__ __launch_bounds__(256) void ret_o2_k(
    const unsigned short* __restrict__ Qb, const unsigned short* __restrict__ Kb,
    const unsigned short* __restrict__ Vb, const unsigned short* __restrict__ Sg,
    const unsigned short* __restrict__ Gg, const float* __restrict__ gnw,
    const float* __restrict__ gnb, unsigned short* __restrict__ Sb)
{
  __shared__ __align__(16) unsigned short Qs[64 * 64];    // swizzled
  __shared__ __align__(16) unsigned short Ks[64 * 64];    // swizzled
  __shared__ __align__(16) unsigned short Ss[64 * 64];    // swizzled (pre-swz global)
  __shared__ __align__(16) unsigned short Vst[64 * LDST]; // [d2][m]
  __shared__ __align__(16) unsigned short Ps[64 * LDST];
  const int c = (int)blockIdx.x;
  const int h = blockIdx.y, b = blockIdx.z;
  const int bh = b * NH + h;
  const int tid = threadIdx.x;
  const int wave = tid >> 6, lane = tid & 63;
  const int n = lane & 15, quad = lane >> 4;
  const size_t base = ((size_t)b * T_SEQ + (size_t)c * 64) * DMODEL + h * DH;
  const float lg = log2f(1.0f - exp2f(-5.0f - (float)h));

  // stage Q, K, S (async; Q/K swizzled at source index, S pre-swizzled content)
  const unsigned short* Sgt = Sg + (((size_t)bh * 32 + (size_t)c) << 12);
  #pragma unroll
  for (int r = 0; r < 2; ++r) {
    int idx = r * 256 + tid;
    int row = idx >> 3, sc = ((idx & 7) ^ (row & 7)) * 8;
    gld16(&Qs[idx * 8], &Qb[base + (size_t)row * DMODEL + sc]);
    gld16(&Ks[idx * 8], &Kb[base + (size_t)row * DMODEL + sc]);
    gld16(&Ss[idx * 8], &Sgt[(size_t)idx * 8]);
  }
  // V^T staging (VGPR transpose path)
  #pragma unroll
  for (int r = 0; r < 2; ++r) {
    int idx = r * 256 + tid;
    int m = idx & 63, ch = idx >> 6;
    s16x8 vv = *(const s16x8*)&Vb[base + (size_t)m * DMODEL + ch * 8];
    #pragma unroll
    for (int e = 0; e < 8; ++e)
      Vst[(ch * 8 + e) * LDST + m] = ((unsigned short*)&vv)[e];
  }
  __syncthreads();  // drains Q/K/S gld16 + Vst writes

  f32x4 s[4], u[4];
  #pragma unroll
  for (int j = 0; j < 4; ++j) {
    s[j] = (f32x4){0.f,0.f,0.f,0.f};
    u[j] = (f32x4){0.f,0.f,0.f,0.f};
  }
  const int RA = wave*16 + n;
  #pragma unroll
  for (int kk = 0; kk < 2; ++kk) {
    s16x8 a = *(const s16x8*)&Qs[RA * 64 + (((kk*4 + quad) ^ (RA & 7)) * 8)];
    #pragma unroll
    for (int j = 0; j < 4; ++j) {
      int RB = j*16 + n;
      int cc = ((kk*4 + quad) ^ (RB & 7)) * 8;
      s16x8 bk = *(const s16x8*)&Ks[RB * 64 + cc];
      s[j] = __builtin_amdgcn_mfma_f32_16x16x32_bf16(a, bk, s[j], 0, 0, 0);
      s16x8 bs = *(const s16x8*)&Ss[RB * 64 + cc];
      u[j] = __builtin_amdgcn_mfma_f32_16x16x32_bf16(a, bs, u[j], 0, 0, 0);
    }
  }

  float rowf[4], colf[4];
  #pragma unroll
  for (int r = 0; r < 4; ++r) rowf[r] = exp2f((float)(wave*16 + quad*4 + r) * lg);
  #pragma unroll
  for (int j = 0; j < 4; ++j) colf[j] = exp2f(-(float)(j*16 + n) * lg);

  #pragma unroll
  for (int j = 0; j < 4; ++j)
    #pragma unroll
    for (int r = 0; r < 4; ++r) {
      int i = wave*16 + quad*4 + r, mcol = j*16 + n;
      float v = (mcol <= i) ? s[j][r] * 0.125f * rowf[r] * colf[j] : 0.0f;
      Ps[i * LDST + mcol] = f2bf(v);
    }
  __syncthreads();  // all QK reads of Qs done; Ps ready

  // prefetch G tile into Qs (now dead) for the epilogue
  #pragma unroll
  for (int r = 0; r < 2; ++r) {
    int idx = r * 256 + tid;
    int row = idx >> 3, sc = ((idx & 7) ^ (row & 7)) * 8;
    gld16(&Qs[idx * 8], &Gg[base + (size_t)row * DMODEL + sc]);
  }

  f32x4 acc[4];
  #pragma unroll
  for (int j = 0; j < 4; ++j) acc[j] = (f32x4){0.f,0.f,0.f,0.f};
  #pragma unroll
  for (int kk = 0; kk < 2; ++kk) {
    s16x8 a = *(const s16x8*)&Ps[RA * LDST + kk*32 + quad*8];
    #pragma unroll
    for (int j = 0; j < 4; ++j) {
      s16x8 bf = *(const s16x8*)&Vst[(j*16 + n) * LDST + kk*32 + quad*8];
      acc[j] = __builtin_amdgcn_mfma_f32_16x16x32_bf16(a, bf, acc[j], 0, 0, 0);
    }
  }

  float ov[4][4];
  #pragma unroll
  for (int j = 0; j < 4; ++j)
    #pragma unroll
    for (int r = 0; r < 4; ++r)
      ov[j][r] = acc[j][r] + 0.125f * rowf[r] * u[j][r];

  float gw[4], gb[4];
  #pragma unroll
  for (int j = 0; j < 4; ++j) {
    gw[j] = gnw[h*DH + j*16 + n];
    gb[j] = gnb[h*DH + j*16 + n];
  }

  float normed[4][4];
  #pragma unroll
  for (int r = 0; r < 4; ++r) {
    float sum = ov[0][r] + ov[1][r] + ov[2][r] + ov[3][r];
    float sq  = ov[0][r]*ov[0][r] + ov[1][r]*ov[1][r]
              + ov[2][r]*ov[2][r] + ov[3][r]*ov[3][r];
    #pragma unroll
    for (int off = 8; off > 0; off >>= 1) {
      sum += __shfl_xor(sum, off, 64);
      sq  += __shfl_xor(sq,  off, 64);
    }
    const float mean = sum * (1.0f / 64.0f);
    float var = sq * (1.0f / 64.0f) - mean * mean;
    var = fmaxf(var, 0.0f);
    const float rstd = rsqrtf(var + 1e-5f);
    #pragma unroll
    for (int j = 0; j < 4; ++j)
      normed[j][r] = (ov[j][r] - mean) * rstd * gw[j] + gb[j];
  }

  __syncthreads();  // all PV reads of Ps done; G gld16 drained

  #pragma unroll
  for (int r = 0; r < 4; ++r) {
    const int i = wave*16 + quad*4 + r;
    #pragma unroll
    for (int j = 0; j < 4; ++j) {
      const int col = j*16 + n;
      const int gidx = i * 64 + (((col >> 3) ^ (i & 7)) * 8) + (col & 7);
      float uu = bf2f(Qs[gidx]) + normed[j][r];
      Ps[i * LDST + col] = f2bf(uu / (1.0f + expf(-uu)));
    }
  }
  __syncthreads();
  #pragma unroll
  for (int t = 0; t < 2; ++t) {
    int idx = t * 256 + tid;
    int row = idx >> 3, u8 = idx & 7;
    *(s16x8*)&Sb[base + (size_t)row * DMODEL + u8 * 8] =
        *(const s16x8*)&Ps[row * LDST + u8 * 8];
  }
}

// ---------------------------------------------------------------------------
// Output GEMM: out = Sb(4096x512 bf16) @ WO^T, fp32. 1-D grid 512 with
// XCD-chunked swizzle: each XCD gets 64 consecutive logical tiles = 8 full
// A row-panels (512KB) + all of WO (512KB) resident in its L2.
// ---------------------------------------------------------------------------
__global__ __launch_bounds__(256) void out_gemm_k(
    const unsigned short* __restrict__ A, const unsigned short* __restrict__ BT,
    float* __restrict__ out)
{
  __shared__ __align__(16) unsigned short As[64 * 64];
  __shared__ __align__(16) unsigned short Bs[64 * 64];
  const int hw = (int)blockIdx.x;
  const int lg = (hw & 7) * 64 + (hw >> 3);   // bijective: 512 = 8 * 64
  const int n0 = (lg & 7) * 64;
  const int m0 = (lg >> 3) * 64;
  const int tid = threadIdx.x;
  const int wave = tid >> 6, lane = tid & 63;
  const int wm = wave >> 1, wn = wave & 1;
  const int n = lane & 15, quad = lane >> 4;

  int srow[2], scol[2];
  #pragma unroll
  for (int r = 0; r < 2; ++r) {
    int idx = r * 256 + tid;
    srow[r] = idx >> 3;
    scol[r] = ((idx & 7) ^ (srow[r] & 7)) * 8;
  }

  f32x4 acc[2][2];
  #pragma unroll
  for (int mi = 0; mi < 2; ++mi)
    #pragma unroll
    for (int ni = 0; ni < 2; ++ni) acc[mi][ni] = (f32x4){0.f,0.f,0.f,0.f};

  for (int k0 = 0; k0 < 512; k0 += 64) {
    #pragma unroll
    for (int r = 0; r < 2; ++r) {
      int idx = r * 256 + tid;
      gld16(&As[idx * 8], &A[(size_t)(m0 + srow[r]) * DMODEL + k0 + scol[r]]);
      gld16(&Bs[idx * 8], &BT[(size_t)(n0 + srow[r]) * DMODEL + k0 + scol[r]]);
    }
    __syncthreads();
    #pragma unroll
    for (int kk = 0; kk < 2; ++kk) {
      s16x8 af[2], bf[2];
      #pragma unroll
      for (int mi = 0; mi < 2; ++mi) {
        int R = wm*32 + mi*16 + n, cc = (kk*4 + quad) ^ (n & 7);
        af[mi] = *(const s16x8*)&As[R * 64 + cc * 8];
      }
      #pragma unroll
      for (int ni = 0; ni < 2; ++ni) {
        int R = wn*32 + ni*16 + n, cc = (kk*4 + quad) ^ (n & 7);
        bf[ni] = *(const s16x8*)&Bs[R * 64 + cc * 8];
      }
      #pragma unroll
      for (int mi = 0; mi < 2; ++mi)
        #pragma unroll
        for (int ni = 0; ni < 2; ++ni)
          acc[mi][ni] = __builtin_amdgcn_mfma_f32_16x16x32_bf16(
              af[mi], bf[ni], acc[mi][ni], 0, 0, 0);
    }
    __syncthreads();
  }

  #pragma unroll
  for (int mi = 0; mi < 2; ++mi)
    #pragma unroll
    for (int ni = 0; ni < 2; ++ni)
      #pragma unroll
      for (int r = 0; r < 4; ++r)
        out[(size_t)(m0 + wm*32 + mi*16 + quad*4 + r) * DMODEL +
            n0 + wn*32 + ni*16 + n] = acc[mi][ni][r];
}

// ---------------------------------------------------------------------------
extern "C" void kernel_launch(void* const* d_in, const int* in_sizes, int n_in,
                              void* d_out, int out_size, void* d_ws, size_t ws_size,
                              hipStream_t stream) {
  const float* x   = (const float*)d_in[0];
  const float* WQ  = (const float*)d_in[1];
  const float* WK  = (const float*)d_in[2];
  const float* WV  = (const float*)d_in[3];
  const float* WG  = (const float*)d_in[4];
  const float* WO  = (const float*)d_in[5];
  const float* gnw = (const float*)d_in[6];
  const float* gnb = (const float*)d_in[7];
  float* out = (float*)d_out;

  char* ws = (char*)d_ws;
  unsigned short* Xb = (unsigned short*)(ws);                 // 4 MB
  unsigned short* Qb = (unsigned short*)(ws + 4  * (1<<20));  // 4 MB
  unsigned short* Kb = (unsigned short*)(ws + 8  * (1<<20));  // 4 MB
  unsigned short* Vb = (unsigned short*)(ws + 12 * (1<<20));  // 4 MB
  unsigned short* G  = (unsigned short*)(ws + 16 * (1<<20));  // 4 MB (bf16)
  float* AT  = (float*)(ws + 24 * (1<<20));                   // 8 MB
  unsigned short* Sb = (unsigned short*)(ws + 32 * (1<<20));  // 4 MB
  unsigned short* Sg = (unsigned short*)(ws + 36 * (1<<20));  // 4 MB (bf16 states)
  unsigned short* WT = (unsigned short*)(ws + 40 * (1<<20));  // 2.5 MB
  (void)ws_size;

  // 1) fused cast-x + weight transpose/stacking
  prep_k<<<dim3(1024 + 320), 256, 0, stream>>>(x, Xb, WQ, WK, WV, WG, WO, WT);
  // 2) projections + fused per-chunk KV outer products (XCD-swizzled)
  proj_kv_k<<<dim3(512), 256, 0, stream>>>(Xb, WT, Qb, Kb, Vb, G, AT);
  // 3) wide sequential prefix scan over chunk states (bf16, pre-swizzled)
  scan_k<<<dim3(64), 256, 0, stream>>>(AT, Sg);
  // 4) fused retention output + GroupNorm + gate + SiLU
  ret_o2_k<<<dim3(T_SEQ / 64, NH, 2), 256, 0, stream>>>(
      Qb, Kb, Vb, Sg, G, gnw, gnb, Sb);
  // 5) output projection (fp32 out), XCD-swizzled 64x64 tiles, 2 blocks/CU
  out_gemm_k<<<dim3(512), 256, 0, stream>>>(Sb, WT + 2048 * DMODEL, out);
}

// Round 5
// 112.467 us; speedup vs baseline: 1.3091x; 1.0078x over previous
//
#include <hip/hip_runtime.h>
#include <hip/hip_bf16.h>
#include <math.h>

#define DMODEL 512
#define T_SEQ 2048
#define NH 8
#define DH 64
#define M_ROWS 4096
#define LDST 72   // padded LDS row stride (retention staging); 144 B = 16B-aligned
#define EPST 136  // epilogue repack stride (272 B = 16B-aligned, 2-way banks)

typedef short s16x8 __attribute__((ext_vector_type(8)));
typedef short s16x4 __attribute__((ext_vector_type(4)));
typedef float f32x4 __attribute__((ext_vector_type(4)));

static __device__ __forceinline__ unsigned short f2bf(float f) {
  __hip_bfloat16 h = __float2bfloat16(f);
  return *(unsigned short*)&h;
}
static __device__ __forceinline__ float bf2f(unsigned short u) {
  union { unsigned int i; float f; } x; x.i = (unsigned int)u << 16; return x.f;
}
// async global->LDS 16B copy; LDS dest must be wave-uniform base + lane*16
static __device__ __forceinline__ void gld16(void* lds, const void* g) {
  __builtin_amdgcn_global_load_lds(
      (const __attribute__((address_space(1))) unsigned int*)g,
      (__attribute__((address_space(3))) unsigned int*)lds, 16, 0, 0);
}

// ---------------------------------------------------------------------------
// Fused prep: blocks 0..1023 cast x -> bf16; blocks 1024..1343 transpose+cast
// the 5 weight matrices into the stacked-row layout:
//   rows    0..511  : W_Q cols | rows 512..1535: [K_h|V_h] x 8 heads
//   rows 1536..2047 : W_G cols | rows 2048..2559: W_O cols
// ---------------------------------------------------------------------------
__global__ __launch_bounds__(256) void prep_k(
    const float* __restrict__ x, unsigned short* __restrict__ Xb,
    const float* __restrict__ W0, const float* __restrict__ W1,
    const float* __restrict__ W2, const float* __restrict__ W3,
    const float* __restrict__ W4, unsigned short* __restrict__ WT)
{
  __shared__ __align__(16) unsigned short buf[64 * LDST];
  const int bid = blockIdx.x, tid = threadIdx.x;
  if (bid < 1024) {
    const size_t i = ((size_t)bid * 256 + tid) * 8;
    float4 a = *(const float4*)&x[i];
    float4 b = *(const float4*)&x[i + 4];
    s16x8 o;
    o[0]=f2bf(a.x); o[1]=f2bf(a.y); o[2]=f2bf(a.z); o[3]=f2bf(a.w);
    o[4]=f2bf(b.x); o[5]=f2bf(b.y); o[6]=f2bf(b.z); o[7]=f2bf(b.w);
    *(s16x8*)&Xb[i] = o;
    return;
  }
  const int bid2 = bid - 1024;
  const int z = bid2 >> 6, rem = bid2 & 63;
  const int n0 = (rem & 7) * 64, k0 = (rem >> 3) * 64;
  const float* W = (z==0)?W0:(z==1)?W1:(z==2)?W2:(z==3)?W3:W4;
  int rowbase;
  if (z == 0)      rowbase = n0;
  else if (z == 1) rowbase = 512 + (n0 >> 6) * 128;        // K_h block
  else if (z == 2) rowbase = 512 + (n0 >> 6) * 128 + 64;   // V_h block
  else if (z == 3) rowbase = 1536 + n0;
  else             rowbase = 2048 + n0;
  #pragma unroll
  for (int r = 0; r < 4; ++r) {
    int idx = r * 256 + tid;
    int kr = idx >> 4, nc = idx & 15;
    float4 v = *(const float4*)&W[(size_t)(k0 + kr) * DMODEL + n0 + nc * 4];
    buf[(nc*4+0) * LDST + kr] = f2bf(v.x);
    buf[(nc*4+1) * LDST + kr] = f2bf(v.y);
    buf[(nc*4+2) * LDST + kr] = f2bf(v.z);
    buf[(nc*4+3) * LDST + kr] = f2bf(v.w);
  }
  __syncthreads();
  #pragma unroll
  for (int r = 0; r < 2; ++r) {
    int idx = r * 256 + tid;
    int nr = idx >> 3, c = idx & 7;
    *(s16x8*)&WT[((size_t)(rowbase + nr)) * DMODEL + k0 + c * 8] =
        *(const s16x8*)&buf[nr * LDST + c * 8];
  }
}

// ---------------------------------------------------------------------------
// Projection GEMM + fused KV outer product; 512 threads / 8 waves (2x4),
// per-wave 64x32 output (acc[4][2]) -> 16 waves/CU = 4 waves/SIMD to hide
// the per-iter vmcnt(0)+barrier drain. XCD-chunked swizzle kept.
// AT epilogue: the two 64-row chunks run in PARALLEL on the wave halves
// (wm = chunk), removing the serial cc2 loop + one barrier round.
// ---------------------------------------------------------------------------
__global__ __launch_bounds__(512) void proj_kv_k(
    const unsigned short* __restrict__ A, const unsigned short* __restrict__ BT,
    unsigned short* __restrict__ Qb, unsigned short* __restrict__ Kb,
    unsigned short* __restrict__ Vb, unsigned short* __restrict__ Gb,
    float* __restrict__ AT)
{
  __shared__ __align__(16) unsigned short smem[4 * 64 * LDST]; // 36.9 KB
  unsigned short* As = smem;                 // 128x64
  unsigned short* Bs = smem + 128 * 64;      // 128x64 (ends at 16384 shorts)
  const int hw = (int)blockIdx.x;
  const int lgid = (hw & 7) * 64 + (hw >> 3);  // bijective: 512 = 8 * 64
  const int bx = lgid & 15, by = lgid >> 4;
  const int ng0 = bx * 128;
  const int m0 = by * 128;
  const int tid = threadIdx.x;
  const int wave = tid >> 6, lane = tid & 63;
  const int wm = wave >> 2, wn = wave & 3;     // 2 x 4 wave grid
  const int n = lane & 15, quad = lane >> 4;

  int srow[2], scol[2];
  #pragma unroll
  for (int r = 0; r < 2; ++r) {
    int idx = r * 512 + tid;
    srow[r] = idx >> 3;
    scol[r] = ((idx & 7) ^ (srow[r] & 7)) * 8;
  }

  f32x4 acc[4][2];
  #pragma unroll
  for (int mi = 0; mi < 4; ++mi)
    #pragma unroll
    for (int ni = 0; ni < 2; ++ni) acc[mi][ni] = (f32x4){0.f,0.f,0.f,0.f};

  for (int k0 = 0; k0 < 512; k0 += 64) {
    #pragma unroll
    for (int r = 0; r < 2; ++r) {
      int idx = r * 512 + tid;
      gld16(&As[idx * 8], &A[(size_t)(m0 + srow[r]) * DMODEL + k0 + scol[r]]);
      gld16(&Bs[idx * 8], &BT[(size_t)(ng0 + srow[r]) * DMODEL + k0 + scol[r]]);
    }
    __syncthreads();
    #pragma unroll
    for (int kk = 0; kk < 2; ++kk) {
      s16x8 af[4], bf[2];
      #pragma unroll
      for (int mi = 0; mi < 4; ++mi) {
        int R = wm*64 + mi*16 + n, cc = (kk*4 + quad) ^ (n & 7);
        af[mi] = *(const s16x8*)&As[R * 64 + cc * 8];
      }
      #pragma unroll
      for (int ni = 0; ni < 2; ++ni) {
        int R = wn*32 + ni*16 + n, cc = (kk*4 + quad) ^ (n & 7);
        bf[ni] = *(const s16x8*)&Bs[R * 64 + cc * 8];
      }
      #pragma unroll
      for (int mi = 0; mi < 4; ++mi)
        #pragma unroll
        for (int ni = 0; ni < 2; ++ni)
          acc[mi][ni] = __builtin_amdgcn_mfma_f32_16x16x32_bf16(
              af[mi], bf[ni], acc[mi][ni], 0, 0, 0);
    }
    __syncthreads();
  }

  // ---- epilogue: repack acc via LDS (128 x EPST) -> b128 global stores ----
  unsigned short* Ep = smem;   // 128*EPST = 17408 shorts <= 18432
  #pragma unroll
  for (int mi = 0; mi < 4; ++mi)
    #pragma unroll
    for (int ni = 0; ni < 2; ++ni)
      #pragma unroll
      for (int r = 0; r < 4; ++r)
        Ep[(wm*64 + mi*16 + quad*4 + r) * EPST + wn*32 + ni*16 + n] =
            f2bf(acc[mi][ni][r]);
  __syncthreads();

  if (bx < 4 || bx >= 12) {
    unsigned short* Cz = (bx < 4) ? Qb : Gb;
    const int n0 = (bx < 4) ? ng0 : (ng0 - 1536);
    #pragma unroll
    for (int t = 0; t < 4; ++t) {
      int idx = t * 512 + tid;
      int row = idx >> 4, u = idx & 15;
      *(s16x8*)&Cz[(size_t)(m0 + row) * DMODEL + n0 + u * 8] =
          *(const s16x8*)&Ep[row * EPST + u * 8];
    }
    return;
  }

  // KV tile: cols 0..63 = K_h, 64..127 = V_h
  const int h = (ng0 - 512) >> 7;
  const float lg2 = log2f(1.0f - exp2f(-5.0f - (float)h));
  #pragma unroll
  for (int t = 0; t < 2; ++t) {
    int idx = t * 512 + tid;
    int row = idx >> 3, u = idx & 7;
    *(s16x8*)&Kb[(size_t)(m0 + row) * DMODEL + h*DH + u * 8] =
        *(const s16x8*)&Ep[row * EPST + u * 8];
    *(s16x8*)&Vb[(size_t)(m0 + row) * DMODEL + h*DH + u * 8] =
        *(const s16x8*)&Ep[row * EPST + 64 + u * 8];
  }

  // fused AT: both 64-row chunks in parallel (chunk = wm). Stage scaled K^T
  // and V^T per chunk, 8 MFMAs per wave, store.
  unsigned short* Kt = smem + wm * (2 * 64 * LDST);  // [d1][m], LDST stride
  unsigned short* Vt = Kt + 64 * LDST;
  __syncthreads();   // all Ep reads done before overwriting smem
  {
    unsigned short* Tt = (wn < 2) ? Kt : Vt;
    #pragma unroll
    for (int mi = 0; mi < 4; ++mi)
      #pragma unroll
      for (int r = 0; r < 4; ++r) {
        int m = mi*16 + quad*4 + r;                  // chunk-local row
        float sc = (wn < 2) ? exp2f((float)(64 - m) * lg2) : 1.0f;
        #pragma unroll
        for (int ni = 0; ni < 2; ++ni) {
          int d1 = (wn & 1)*32 + ni*16 + n;
          Tt[d1 * LDST + m] = f2bf(acc[mi][ni][r] * sc);
        }
      }
  }
  __syncthreads();
  f32x4 at[4];
  #pragma unroll
  for (int j = 0; j < 4; ++j) at[j] = (f32x4){0.f,0.f,0.f,0.f};
  #pragma unroll
  for (int kk = 0; kk < 2; ++kk) {
    s16x8 a = *(const s16x8*)&Vt[(wn*16 + n) * LDST + kk*32 + quad*8];
    #pragma unroll
    for (int j = 0; j < 4; ++j) {
      s16x8 bf = *(const s16x8*)&Kt[(j*16 + n) * LDST + kk*32 + quad*8];
      at[j] = __builtin_amdgcn_mfma_f32_16x16x32_bf16(a, bf, at[j], 0, 0, 0);
    }
  }
  const int gr = m0 + wm * 64;
  const int bb = gr >> 11, cchunk = (gr & 2047) >> 6;
  float* Ab = AT + (((size_t)(bb * NH + h) * 32 + cchunk) << 12);
  #pragma unroll
  for (int j = 0; j < 4; ++j)
    #pragma unroll
    for (int r = 0; r < 4; ++r)
      Ab[(wn*16 + quad*4 + r) * 64 + j*16 + n] = at[j][r];
}

// ---------------------------------------------------------------------------
// Sequential prefix scan over chunk states, WIDE version.
//   S_{c+1} = gamma_h^64 * S_c + A_c,  S_0 = 0
// 64 blocks (4 per (b,h), 16 state-rows each); each thread owns ONE float4
// column slice of one row. #pragma unroll 8 lets 8 iterations' independent
// loads fly while the dependent FMA chain trails (~2 MB in flight chip-wide).
// Emits bf16, pre-XOR-swizzled in the column-block index so ret_o2_k stages
// with linear gld16 and reads with the same XOR pattern as Ks.
// ---------------------------------------------------------------------------
__global__ __launch_bounds__(256) void scan_k(
    const float* __restrict__ AT, unsigned short* __restrict__ Sg)
{
  const int bh = blockIdx.x >> 2;     // b*NH + h, 0..15
  const int rg = blockIdx.x & 3;      // row group (16 rows each)
  const int h = bh & 7;
  const int tid = threadIdx.x;
  const float lg = log2f(1.0f - exp2f(-5.0f - (float)h));
  const float w = exp2f(64.0f * lg);  // gamma^64
  const int d2 = rg * 16 + (tid >> 4);     // state row 0..63
  const int col4 = (tid & 15) * 4;         // first owned column
  const int gcol = (((col4 >> 3) ^ (d2 & 7)) * 8) + (col4 & 7); // swizzled
  const float* Ab = AT + (((size_t)bh * 32) << 12) + (size_t)d2 * 64 + col4;
  unsigned short* Sr = Sg + (((size_t)bh * 32) << 12) + (size_t)d2 * 64 + gcol;
  float4 S = {0.f, 0.f, 0.f, 0.f};
  #pragma unroll 8
  for (int c = 0; c < 32; ++c) {
    float4 a = *(const float4*)(Ab + ((size_t)c << 12));
    s16x4 st;
    st[0] = (short)f2bf(S.x); st[1] = (short)f2bf(S.y);
    st[2] = (short)f2bf(S.z); st[3] = (short)f2bf(S.w);
    *(s16x4*)(Sr + ((size_t)c << 12)) = st;   // 8B store, 8B-aligned
    S.x = fmaf(w, S.x, a.x); S.y = fmaf(w, S.y, a.y);
    S.z = fmaf(w, S.z, a.z); S.w = fmaf(w, S.w, a.w);
  }
}

// ---------------------------------------------------------------------------
// Fused retention output + GroupNorm + gate + SiLU. S_c staged via gld16.
// No XCD swizzle: blocks sharing a row-panel (same c) are stride-32 apart in
// dispatch order and 32%8==0, so they already co-locate per XCD.
// ---------------------------------------------------------------------------
__global__ __launch_bounds__(256) void ret_o2_k(
    const unsigned short* __restrict__ Qb, const unsigned short* __restrict__ Kb,
    const unsigned short* __restrict__ Vb, const unsigned short* __restrict__ Sg,
    const unsigned short* __restrict__ Gg, const float* __restrict__ gnw,
    const float* __restrict__ gnb, unsigned short* __restrict__ Sb)
{
  __shared__ __align__(16) unsigned short Qs[64 * 64];    // swizzled
  __shared__ __align__(16) unsigned short Ks[64 * 64];    // swizzled
  __shared__ __align__(16) unsigned short Ss[64 * 64];    // swizzled (pre-swz global)
  __shared__ __align__(16) unsigned short Vst[64 * LDST]; // [d2][m]
  __shared__ __align__(16) unsigned short Ps[64 * LDST];
  const int c = (int)blockIdx.x;
  const int h = blockIdx.y, b = blockIdx.z;
  const int bh = b * NH + h;
  const int tid = threadIdx.x;
  const int wave = tid >> 6, lane = tid & 63;
  const int n = lane & 15, quad = lane >> 4;
  const size_t base = ((size_t)b * T_SEQ + (size_t)c * 64) * DMODEL + h * DH;
  const float lg = log2f(1.0f - exp2f(-5.0f - (float)h));

  // stage Q, K, S (async; Q/K swizzled at source index, S pre-swizzled content)
  const unsigned short* Sgt = Sg + (((size_t)bh * 32 + (size_t)c) << 12);
  #pragma unroll
  for (int r = 0; r < 2; ++r) {
    int idx = r * 256 + tid;
    int row = idx >> 3, sc = ((idx & 7) ^ (row & 7)) * 8;
    gld16(&Qs[idx * 8], &Qb[base + (size_t)row * DMODEL + sc]);
    gld16(&Ks[idx * 8], &Kb[base + (size_t)row * DMODEL + sc]);
    gld16(&Ss[idx * 8], &Sgt[(size_t)idx * 8]);
  }
  // V^T staging (VGPR transpose path)
  #pragma unroll
  for (int r = 0; r < 2; ++r) {
    int idx = r * 256 + tid;
    int m = idx & 63, ch = idx >> 6;
    s16x8 vv = *(const s16x8*)&Vb[base + (size_t)m * DMODEL + ch * 8];
    #pragma unroll
    for (int e = 0; e < 8; ++e)
      Vst[(ch * 8 + e) * LDST + m] = ((unsigned short*)&vv)[e];
  }
  __syncthreads();  // drains Q/K/S gld16 + Vst writes

  f32x4 s[4], u[4];
  #pragma unroll
  for (int j = 0; j < 4; ++j) {
    s[j] = (f32x4){0.f,0.f,0.f,0.f};
    u[j] = (f32x4){0.f,0.f,0.f,0.f};
  }
  const int RA = wave*16 + n;
  #pragma unroll
  for (int kk = 0; kk < 2; ++kk) {
    s16x8 a = *(const s16x8*)&Qs[RA * 64 + (((kk*4 + quad) ^ (RA & 7)) * 8)];
    #pragma unroll
    for (int j = 0; j < 4; ++j) {
      int RB = j*16 + n;
      int cc = ((kk*4 + quad) ^ (RB & 7)) * 8;
      s16x8 bk = *(const s16x8*)&Ks[RB * 64 + cc];
      s[j] = __builtin_amdgcn_mfma_f32_16x16x32_bf16(a, bk, s[j], 0, 0, 0);
      s16x8 bs = *(const s16x8*)&Ss[RB * 64 + cc];
      u[j] = __builtin_amdgcn_mfma_f32_16x16x32_bf16(a, bs, u[j], 0, 0, 0);
    }
  }

  float rowf[4], colf[4];
  #pragma unroll
  for (int r = 0; r < 4; ++r) rowf[r] = exp2f((float)(wave*16 + quad*4 + r) * lg);
  #pragma unroll
  for (int j = 0; j < 4; ++j) colf[j] = exp2f(-(float)(j*16 + n) * lg);

  #pragma unroll
  for (int j = 0; j < 4; ++j)
    #pragma unroll
    for (int r = 0; r < 4; ++r) {
      int i = wave*16 + quad*4 + r, mcol = j*16 + n;
      float v = (mcol <= i) ? s[j][r] * 0.125f * rowf[r] * colf[j] : 0.0f;
      Ps[i * LDST + mcol] = f2bf(v);
    }
  __syncthreads();  // all QK reads of Qs done; Ps ready

  // prefetch G tile into Qs (now dead) for the epilogue
  #pragma unroll
  for (int r = 0; r < 2; ++r) {
    int idx = r * 256 + tid;
    int row = idx >> 3, sc = ((idx & 7) ^ (row & 7)) * 8;
    gld16(&Qs[idx * 8], &Gg[base + (size_t)row * DMODEL + sc]);
  }

  f32x4 acc[4];
  #pragma unroll
  for (int j = 0; j < 4; ++j) acc[j] = (f32x4){0.f,0.f,0.f,0.f};
  #pragma unroll
  for (int kk = 0; kk < 2; ++kk) {
    s16x8 a = *(const s16x8*)&Ps[RA * LDST + kk*32 + quad*8];
    #pragma unroll
    for (int j = 0; j < 4; ++j) {
      s16x8 bf = *(const s16x8*)&Vst[(j*16 + n) * LDST + kk*32 + quad*8];
      acc[j] = __builtin_amdgcn_mfma_f32_16x16x32_bf16(a, bf, acc[j], 0, 0, 0);
    }
  }

  float ov[4][4];
  #pragma unroll
  for (int j = 0; j < 4; ++j)
    #pragma unroll
    for (int r = 0; r < 4; ++r)
      ov[j][r] = acc[j][r] + 0.125f * rowf[r] * u[j][r];

  float gw[4], gb[4];
  #pragma unroll
  for (int j = 0; j < 4; ++j) {
    gw[j] = gnw[h*DH + j*16 + n];
    gb[j] = gnb[h*DH + j*16 + n];
  }

  float normed[4][4];
  #pragma unroll
  for (int r = 0; r < 4; ++r) {
    float sum = ov[0][r] + ov[1][r] + ov[2][r] + ov[3][r];
    float sq  = ov[0][r]*ov[0][r] + ov[1][r]*ov[1][r]
              + ov[2][r]*ov[2][r] + ov[3][r]*ov[3][r];
    #pragma unroll
    for (int off = 8; off > 0; off >>= 1) {
      sum += __shfl_xor(sum, off, 64);
      sq  += __shfl_xor(sq,  off, 64);
    }
    const float mean = sum * (1.0f / 64.0f);
    float var = sq * (1.0f / 64.0f) - mean * mean;
    var = fmaxf(var, 0.0f);
    const float rstd = rsqrtf(var + 1e-5f);
    #pragma unroll
    for (int j = 0; j < 4; ++j)
      normed[j][r] = (ov[j][r] - mean) * rstd * gw[j] + gb[j];
  }

  __syncthreads();  // all PV reads of Ps done; G gld16 drained

  #pragma unroll
  for (int r = 0; r < 4; ++r) {
    const int i = wave*16 + quad*4 + r;
    #pragma unroll
    for (int j = 0; j < 4; ++j) {
      const int col = j*16 + n;
      const int gidx = i * 64 + (((col >> 3) ^ (i & 7)) * 8) + (col & 7);
      float uu = bf2f(Qs[gidx]) + normed[j][r];
      Ps[i * LDST + col] = f2bf(uu / (1.0f + expf(-uu)));
    }
  }
  __syncthreads();
  #pragma unroll
  for (int t = 0; t < 2; ++t) {
    int idx = t * 256 + tid;
    int row = idx >> 3, u8 = idx & 7;
    *(s16x8*)&Sb[base + (size_t)row * DMODEL + u8 * 8] =
        *(const s16x8*)&Ps[row * LDST + u8 * 8];
  }
}

// ---------------------------------------------------------------------------
// Output GEMM: out = Sb(4096x512 bf16) @ WO^T, fp32. 1-D grid 512 with
// XCD-chunked swizzle: each XCD gets 64 consecutive logical tiles = 8 full
// A row-panels (512KB) + all of WO (512KB) resident in its L2.
// ---------------------------------------------------------------------------
__global__ __launch_bounds__(256) void out_gemm_k(
    const unsigned short* __restrict__ A, const unsigned short* __restrict__ BT,
    float* __restrict__ out)
{
  __shared__ __align__(16) unsigned short As[64 * 64];
  __shared__ __align__(16) unsigned short Bs[64 * 64];
  const int hw = (int)blockIdx.x;
  const int lgid = (hw & 7) * 64 + (hw >> 3);   // bijective: 512 = 8 * 64
  const int n0 = (lgid & 7) * 64;
  const int m0 = (lgid >> 3) * 64;
  const int tid = threadIdx.x;
  const int wave = tid >> 6, lane = tid & 63;
  const int wm = wave >> 1, wn = wave & 1;
  const int n = lane & 15, quad = lane >> 4;

  int srow[2], scol[2];
  #pragma unroll
  for (int r = 0; r < 2; ++r) {
    int idx = r * 256 + tid;
    srow[r] = idx >> 3;
    scol[r] = ((idx & 7) ^ (srow[r] & 7)) * 8;
  }

  f32x4 acc[2][2];
  #pragma unroll
  for (int mi = 0; mi < 2; ++mi)
    #pragma unroll
    for (int ni = 0; ni < 2; ++ni) acc[mi][ni] = (f32x4){0.f,0.f,0.f,0.f};

  for (int k0 = 0; k0 < 512; k0 += 64) {
    #pragma unroll
    for (int r = 0; r < 2; ++r) {
      int idx = r * 256 + tid;
      gld16(&As[idx * 8], &A[(size_t)(m0 + srow[r]) * DMODEL + k0 + scol[r]]);
      gld16(&Bs[idx * 8], &BT[(size_t)(n0 + srow[r]) * DMODEL + k0 + scol[r]]);
    }
    __syncthreads();
    #pragma unroll
    for (int kk = 0; kk < 2; ++kk) {
      s16x8 af[2], bf[2];
      #pragma unroll
      for (int mi = 0; mi < 2; ++mi) {
        int R = wm*32 + mi*16 + n, cc = (kk*4 + quad) ^ (n & 7);
        af[mi] = *(const s16x8*)&As[R * 64 + cc * 8];
      }
      #pragma unroll
      for (int ni = 0; ni < 2; ++ni) {
        int R = wn*32 + ni*16 + n, cc = (kk*4 + quad) ^ (n & 7);
        bf[ni] = *(const s16x8*)&Bs[R * 64 + cc * 8];
      }
      #pragma unroll
      for (int mi = 0; mi < 2; ++mi)
        #pragma unroll
        for (int ni = 0; ni < 2; ++ni)
          acc[mi][ni] = __builtin_amdgcn_mfma_f32_16x16x32_bf16(
              af[mi], bf[ni], acc[mi][ni], 0, 0, 0);
    }
    __syncthreads();
  }

  #pragma unroll
  for (int mi = 0; mi < 2; ++mi)
    #pragma unroll
    for (int ni = 0; ni < 2; ++ni)
      #pragma unroll
      for (int r = 0; r < 4; ++r)
        out[(size_t)(m0 + wm*32 + mi*16 + quad*4 + r) * DMODEL +
            n0 + wn*32 + ni*16 + n] = acc[mi][ni][r];
}

// ---------------------------------------------------------------------------
extern "C" void kernel_launch(void* const* d_in, const int* in_sizes, int n_in,
                              void* d_out, int out_size, void* d_ws, size_t ws_size,
                              hipStream_t stream) {
  const float* x   = (const float*)d_in[0];
  const float* WQ  = (const float*)d_in[1];
  const float* WK  = (const float*)d_in[2];
  const float* WV  = (const float*)d_in[3];
  const float* WG  = (const float*)d_in[4];
  const float* WO  = (const float*)d_in[5];
  const float* gnw = (const float*)d_in[6];
  const float* gnb = (const float*)d_in[7];
  float* out = (float*)d_out;

  char* ws = (char*)d_ws;
  unsigned short* Xb = (unsigned short*)(ws);                 // 4 MB
  unsigned short* Qb = (unsigned short*)(ws + 4  * (1<<20));  // 4 MB
  unsigned short* Kb = (unsigned short*)(ws + 8  * (1<<20));  // 4 MB
  unsigned short* Vb = (unsigned short*)(ws + 12 * (1<<20));  // 4 MB
  unsigned short* G  = (unsigned short*)(ws + 16 * (1<<20));  // 4 MB (bf16)
  float* AT  = (float*)(ws + 24 * (1<<20));                   // 8 MB
  unsigned short* Sb = (unsigned short*)(ws + 32 * (1<<20));  // 4 MB
  unsigned short* Sg = (unsigned short*)(ws + 36 * (1<<20));  // 4 MB (bf16 states)
  unsigned short* WT = (unsigned short*)(ws + 40 * (1<<20));  // 2.5 MB
  (void)ws_size;

  // 1) fused cast-x + weight transpose/stacking
  prep_k<<<dim3(1024 + 320), 256, 0, stream>>>(x, Xb, WQ, WK, WV, WG, WO, WT);
  // 2) projections + fused per-chunk KV outer products (8 waves, XCD-swizzled)
  proj_kv_k<<<dim3(512), 512, 0, stream>>>(Xb, WT, Qb, Kb, Vb, G, AT);
  // 3) wide sequential prefix scan over chunk states (bf16, pre-swizzled)
  scan_k<<<dim3(64), 256, 0, stream>>>(AT, Sg);
  // 4) fused retention output + GroupNorm + gate + SiLU
  ret_o2_k<<<dim3(T_SEQ / 64, NH, 2), 256, 0, stream>>>(
      Qb, Kb, Vb, Sg, G, gnw, gnb, Sb);
  // 5) output projection (fp32 out), XCD-swizzled 64x64 tiles, 2 blocks/CU
  out_gemm_k<<<dim3(512), 256, 0, stream>>>(Sb, WT + 2048 * DMODEL, out);
}